// Round 2
// baseline (164.080 us; speedup 1.0000x reference)
//
#include <hip/hip_runtime.h>
#include <hip/hip_bf16.h>

#define N_ROWS 4096
#define DIM    512
#define M_ROWS 8192
#define BK     32
#define NITER  (DIM / BK)      // 16
#define TILE_E (128 * BK)      // shorts per stage tile (8 KB)
// exp(sim/0.1) = exp2(sim * 10*log2(e))
#define EXP_SCALE 14.4269504088896340736f

typedef unsigned short ushort_t;
typedef __attribute__((ext_vector_type(8))) short short8;
typedef __attribute__((ext_vector_type(4))) float f32x4;

// float -> bf16 bits, round-to-nearest-even (inputs are finite)
__device__ __forceinline__ ushort_t f2bf(float x) {
  unsigned int bits = __float_as_uint(x);
  unsigned int lsb = (bits >> 16) & 1u;
  bits += 0x7fffu + lsb;
  return (ushort_t)(bits >> 16);
}

__device__ __forceinline__ void store4bf(ushort_t* p, float4 v, float s) {
  union { ushort_t u[4]; uint2 d; } pk;
  pk.u[0] = f2bf(v.x * s);
  pk.u[1] = f2bf(v.y * s);
  pk.u[2] = f2bf(v.z * s);
  pk.u[3] = f2bf(v.w * s);
  *(uint2*)p = pk.d;
}

// async global -> LDS, 16 bytes per lane (lds dest = wave-uniform base + lane*16)
__device__ __forceinline__ void async16(const ushort_t* g, ushort_t* l) {
  __builtin_amdgcn_global_load_lds(
      (const __attribute__((address_space(1))) void*)g,
      (__attribute__((address_space(3))) void*)l,
      16, 0, 0);
}

// ---------------------------------------------------------------------------
// Kernel 1: per-row L2 normalize (fp32 math), emit bf16 reps[8192][512] and
// exact fp32 positives pos[i] = dot(z_i, z_j). One wave per row-pair.
// ---------------------------------------------------------------------------
__global__ __launch_bounds__(256) void norm_kernel(
    const float* __restrict__ ei, const float* __restrict__ ej,
    ushort_t* __restrict__ reps, float* __restrict__ pos) {
  int b = blockIdx.x * 4 + (threadIdx.x >> 6);
  int lane = threadIdx.x & 63;
  const float4* pi = (const float4*)(ei + (size_t)b * DIM);
  const float4* pj = (const float4*)(ej + (size_t)b * DIM);
  float4 a0 = pi[lane];
  float4 a1 = pi[lane + 64];
  float4 b0 = pj[lane];
  float4 b1 = pj[lane + 64];

  float si = a0.x*a0.x + a0.y*a0.y + a0.z*a0.z + a0.w*a0.w
           + a1.x*a1.x + a1.y*a1.y + a1.z*a1.z + a1.w*a1.w;
  float sj = b0.x*b0.x + b0.y*b0.y + b0.z*b0.z + b0.w*b0.w
           + b1.x*b1.x + b1.y*b1.y + b1.z*b1.z + b1.w*b1.w;
  float dp = a0.x*b0.x + a0.y*b0.y + a0.z*b0.z + a0.w*b0.w
           + a1.x*b1.x + a1.y*b1.y + a1.z*b1.z + a1.w*b1.w;

#pragma unroll
  for (int m = 32; m >= 1; m >>= 1) {
    si += __shfl_xor(si, m, 64);
    sj += __shfl_xor(sj, m, 64);
    dp += __shfl_xor(dp, m, 64);
  }
  float ii = 1.0f / fmaxf(sqrtf(si), 1e-12f);
  float ij = 1.0f / fmaxf(sqrtf(sj), 1e-12f);
  if (lane == 0) pos[b] = dp * ii * ij;

  ushort_t* ri = reps + (size_t)b * DIM;
  ushort_t* rj = reps + (size_t)(b + N_ROWS) * DIM;
  store4bf(ri + lane * 4,       a0, ii);
  store4bf(ri + 256 + lane * 4, a1, ii);
  store4bf(rj + lane * 4,       b0, ij);
  store4bf(rj + 256 + lane * 4, b1, ij);
}

// ---------------------------------------------------------------------------
// Kernel 2: fused sim-GEMM + exp + masked row/col reduction.
// Triangular grid (2080 blocks), 128x128 tile, 4 waves x (4x4) 16x16x32 MFMA.
// Double-buffered LDS, one barrier per K-iter, prefetch in flight during MFMA.
// LDS staged XOR-swizzled (chunk^= row&3) via the per-lane global source addr
// so fragment ds_read_b128 are <=2-way bank aliased (free).
// ---------------------------------------------------------------------------
__global__ __launch_bounds__(256) void sim_kernel(
    const ushort_t* __restrict__ reps, float* __restrict__ denom) {
  // decode triangular pair (bi <= bj) from linear block id
  int t = blockIdx.x;
  int bi = (int)((129.0f - sqrtf((float)(16641 - 8 * t))) * 0.5f);
  while (bi * (129 - bi) / 2 > t) --bi;
  while ((bi + 1) * (128 - bi) / 2 <= t) ++bi;
  int bj = bi + (t - bi * (129 - bi) / 2);

  __shared__ ushort_t As[2][TILE_E];
  __shared__ ushort_t Bs[2][TILE_E];

  int tid  = threadIdx.x;
  int wave = tid >> 6, lane = tid & 63;
  int wr = wave >> 1, wc = wave & 1;
  int quad = lane >> 4, l15 = lane & 15;

  // staging: chunk c (16 rows) = LDS shorts [c*512, c*512+512). Within a chunk
  // lane's slot is (row = lane>>2, k-chunk = lane&3); XOR-swizzle the global
  // k-chunk so LDS slot (r,c) holds global chunk c^(r&3).
  int c0 = wave * 2, c1 = c0 + 1;
  int srow  = lane >> 2;
  int selem = (((lane & 3) ^ (srow & 3)) * 8);
  const ushort_t* gA0 = reps + (size_t)(bi * 128 + c0 * 16 + srow) * DIM + selem;
  const ushort_t* gA1 = reps + (size_t)(bi * 128 + c1 * 16 + srow) * DIM + selem;
  const ushort_t* gB0 = reps + (size_t)(bj * 128 + c0 * 16 + srow) * DIM + selem;
  const ushort_t* gB1 = reps + (size_t)(bj * 128 + c1 * 16 + srow) * DIM + selem;
  int c0o = c0 * 512, c1o = c1 * 512;

  f32x4 zero4 = {0.0f, 0.0f, 0.0f, 0.0f};
  f32x4 acc[4][4];
#pragma unroll
  for (int tr = 0; tr < 4; ++tr)
#pragma unroll
    for (int tc = 0; tc < 4; ++tc) acc[tr][tc] = zero4;

  // fragment read swizzle: row R's k-chunk `quad` lives at chunk quad^(R&3)
  int sw = (quad ^ (l15 & 3)) * 8;

  // prologue: stage 0 into buffer 0
  async16(gA0, &As[0][c0o]);
  async16(gA1, &As[0][c1o]);
  async16(gB0, &Bs[0][c0o]);
  async16(gB1, &Bs[0][c1o]);

  for (int k = 0; k < NITER; ++k) {
    __syncthreads();  // stage k visible; prior readers of buffer (k+1)&1 done
    if (k + 1 < NITER) {
      int off = (k + 1) * BK;
      int nb = (k + 1) & 1;
      async16(gA0 + off, &As[nb][c0o]);
      async16(gA1 + off, &As[nb][c1o]);
      async16(gB0 + off, &Bs[nb][c0o]);
      async16(gB1 + off, &Bs[nb][c1o]);
    }
    int cb = k & 1;
    short8 aF[4], bF[4];
#pragma unroll
    for (int tt = 0; tt < 4; ++tt) {
      aF[tt] = *(const short8*)(&As[cb][(wr * 64 + tt * 16 + l15) * BK + sw]);
      bF[tt] = *(const short8*)(&Bs[cb][(wc * 64 + tt * 16 + l15) * BK + sw]);
    }
#pragma unroll
    for (int tr = 0; tr < 4; ++tr)
#pragma unroll
      for (int tc = 0; tc < 4; ++tc)
        acc[tr][tc] = __builtin_amdgcn_mfma_f32_16x16x32_bf16(
            aF[tr], bF[tc], acc[tr][tc], 0, 0, 0);
  }

  // epilogue: e = exp(sim/T), mask diagonal, row sums + (off-diag) col sums.
  // C layout: col = l15 (+ tc*16), row = quad*4 + r (+ tr*16)  [m89/m91]
  int rowg_base = bi * 128 + wr * 64;
  int colg_base = bj * 128 + wc * 64;

  f32x4 rsum[4];
  float csum[4] = {0.0f, 0.0f, 0.0f, 0.0f};
#pragma unroll
  for (int tr = 0; tr < 4; ++tr) rsum[tr] = zero4;

#pragma unroll
  for (int tr = 0; tr < 4; ++tr) {
    int rowg0 = rowg_base + tr * 16 + quad * 4;
#pragma unroll
    for (int tc = 0; tc < 4; ++tc) {
      int colg = colg_base + tc * 16 + l15;
      f32x4 a = acc[tr][tc];
      f32x4 e;
#pragma unroll
      for (int r = 0; r < 4; ++r) {
        float v = exp2f(a[r] * EXP_SCALE);
        e[r] = ((rowg0 + r) == colg) ? 0.0f : v;
      }
      rsum[tr] += e;
      csum[tc] += e[0] + e[1] + e[2] + e[3];
    }
  }

  // reduce row sums across the 16 lanes sharing `quad` (masks 1,2,4,8)
#pragma unroll
  for (int m = 1; m <= 8; m <<= 1)
#pragma unroll
    for (int tr = 0; tr < 4; ++tr)
#pragma unroll
      for (int r = 0; r < 4; ++r)
        rsum[tr][r] += __shfl_xor(rsum[tr][r], m, 64);

  if (l15 == 0) {
#pragma unroll
    for (int tr = 0; tr < 4; ++tr)
#pragma unroll
      for (int r = 0; r < 4; ++r)
        atomicAdd(&denom[rowg_base + tr * 16 + quad * 4 + r], rsum[tr][r]);
  }

  if (bi != bj) {
    // reduce col sums across quads (masks 16,32)
#pragma unroll
    for (int m = 16; m <= 32; m <<= 1)
#pragma unroll
      for (int tc = 0; tc < 4; ++tc)
        csum[tc] += __shfl_xor(csum[tc], m, 64);
    if (quad == 0) {
#pragma unroll
      for (int tc = 0; tc < 4; ++tc)
        atomicAdd(&denom[colg_base + tc * 16 + l15], csum[tc]);
    }
  }
}

// ---------------------------------------------------------------------------
// Kernel 3: loss = mean over rows of [log(denom) - pos/T]
// ---------------------------------------------------------------------------
__global__ __launch_bounds__(1024) void loss_kernel(
    const float* __restrict__ denom, const float* __restrict__ pos,
    float* __restrict__ out) {
  __shared__ float red[16];
  int tid = threadIdx.x;
  float p = 0.0f;
  for (int r = tid; r < M_ROWS; r += 1024)
    p += logf(denom[r]) - pos[r & (N_ROWS - 1)] * 10.0f;
#pragma unroll
  for (int m = 32; m >= 1; m >>= 1) p += __shfl_xor(p, m, 64);
  if ((tid & 63) == 0) red[tid >> 6] = p;
  __syncthreads();
  if (tid == 0) {
    float s = 0.0f;
#pragma unroll
    for (int w = 0; w < 16; ++w) s += red[w];
    out[0] = s * (1.0f / M_ROWS);
  }
}

extern "C" void kernel_launch(void* const* d_in, const int* in_sizes, int n_in,
                              void* d_out, int out_size, void* d_ws, size_t ws_size,
                              hipStream_t stream) {
  const float* ei = (const float*)d_in[0];
  const float* ej = (const float*)d_in[1];
  float* out = (float*)d_out;

  char* ws = (char*)d_ws;
  ushort_t* reps = (ushort_t*)ws;                                    // 8 MB bf16
  float* denom = (float*)(ws + (size_t)M_ROWS * DIM * 2);            // 32 KB
  float* pos = (float*)(ws + (size_t)M_ROWS * DIM * 2 + M_ROWS * 4); // 16 KB

  hipMemsetAsync(denom, 0, M_ROWS * sizeof(float), stream);
  norm_kernel<<<N_ROWS / 4, 256, 0, stream>>>(ei, ej, reps, pos);
  sim_kernel<<<2080, 256, 0, stream>>>(reps, denom);
  loss_kernel<<<1, 1024, 0, stream>>>(denom, pos, out);
}